// Round 1
// baseline (3013.399 us; speedup 1.0000x reference)
//
#include <hip/hip_runtime.h>
#include <math.h>

// Problem constants (Swin-V2 window attention)
//  B_=1152 windows, N=64 tokens, C=384 channels, H=12 heads, Dh=32
#define NB   1152
#define NTOK 64
#define NC   384
#define NH   12
#define NDH  32

// ---------------------------------------------------------------------------
// K1: continuous-position-bias MLP (225 rel positions, 2->512->12) + gather +
//     16*sigmoid  ->  bias[H][64][64] in workspace.
// ---------------------------------------------------------------------------
__global__ __launch_bounds__(256) void cpb_kernel(
    const float* __restrict__ w1, const float* __restrict__ b1,
    const float* __restrict__ w2, const float* __restrict__ b2,
    float* __restrict__ bias)
{
    __shared__ float tbs[225][12];
    const int tid = threadIdx.x;

    if (tid < 225) {
        const int ip = tid / 15, jp = tid % 15;
        // table[i,j] = ( g(j-7), g(i-7) ),  g(u) = sign(t)*log2(|t|+1)/3, t = u*8/7
        float u0 = (float)(jp - 7) * (8.0f / 7.0f);
        float u1 = (float)(ip - 7) * (8.0f / 7.0f);
        float s0 = (u0 > 0.f) ? 1.f : ((u0 < 0.f) ? -1.f : 0.f);
        float s1 = (u1 > 0.f) ? 1.f : ((u1 < 0.f) ? -1.f : 0.f);
        float in0 = s0 * log2f(fabsf(u0) + 1.0f) * (1.0f / 3.0f);
        float in1 = s1 * log2f(fabsf(u1) + 1.0f) * (1.0f / 3.0f);

        float acc[12];
        #pragma unroll
        for (int m = 0; m < 12; ++m) acc[m] = b2[m];
        for (int j = 0; j < 512; ++j) {
            float hh = fmaxf(in0 * w1[j] + in1 * w1[512 + j] + b1[j], 0.0f);
            #pragma unroll
            for (int m = 0; m < 12; ++m) acc[m] += hh * w2[j * 12 + m];
        }
        #pragma unroll
        for (int m = 0; m < 12; ++m) tbs[tid][m] = acc[m];
    }
    __syncthreads();

    for (int t = tid; t < NH * NTOK * NTOK; t += 256) {
        const int h   = t >> 12;
        const int rem = t & 4095;
        const int ti  = rem >> 6, tj = rem & 63;
        const int dr = (ti >> 3) - (tj >> 3);
        const int dc = (ti & 7)  - (tj & 7);
        const int p  = (dr + 7) * 15 + (dc + 7);
        const float xv = tbs[p][h];
        bias[t] = 16.0f / (1.0f + __expf(-xv));
    }
}

// ---------------------------------------------------------------------------
// K2: fused per-window QKV projection + cosine attention.
//   grid = 1152 blocks (one window), 256 threads (4 waves).
//   Per head: GEMM x(64x384) @ [wq|wk|wv](384x96) -> q,k,v in LDS,
//   norms, S = q.kT/denom*ls + bias + mask, softmax, O = P.v -> d_out.
// ---------------------------------------------------------------------------
__global__ __launch_bounds__(256) void attn_kernel(
    const float* __restrict__ x,    const float* __restrict__ mask,
    const float* __restrict__ wq,   const float* __restrict__ bq,
    const float* __restrict__ wk,   const float* __restrict__ wv,
    const float* __restrict__ bv,   const float* __restrict__ tau,
    const float* __restrict__ bias, float* __restrict__ out)
{
    __shared__ float xs[16][68];     // x K-chunk, transposed: xs[k][row]
    __shared__ float wt[16][100];    // weight chunk: cols 0..31 q, 32..63 k, 64..95 v
    __shared__ float qsT[32][64];    // q transposed  [d][row]   (bias added)
    __shared__ float ksT[32][64];    // k transposed  [d][col]
    __shared__ float vs[64][32];     // v             [row][d]   (bias added)
    __shared__ float Ss[64][68];     // softmax probs [row][col]
    __shared__ float qn[64], kn[64];

    const int tid = threadIdx.x;
    const int b   = blockIdx.x;
    const int tr  = tid >> 4;   // 0..15  (row group: rows tr*4..tr*4+3)
    const int tc  = tid & 15;   // 0..15

    for (int h = 0; h < NH; ++h) {
        const float ls = fmaxf(tau[h] + 2.302585093f, 0.01f);

        // ---------------- QKV mini-GEMM: out 64x96, K = 384 ----------------
        float acc[4][6];
        #pragma unroll
        for (int i = 0; i < 4; ++i)
            #pragma unroll
            for (int j = 0; j < 6; ++j) acc[i][j] = 0.0f;

        for (int kk = 0; kk < 24; ++kk) {
            // stage x chunk (64 rows x 16 k), transposed
            {
                const int r  = tid >> 2;
                const int c4 = (tid & 3) << 2;
                const float4 xv = *(const float4*)&x[((size_t)b * NTOK + r) * NC + kk * 16 + c4];
                xs[c4 + 0][r] = xv.x; xs[c4 + 1][r] = xv.y;
                xs[c4 + 2][r] = xv.z; xs[c4 + 3][r] = xv.w;
            }
            // stage weight chunk (16 k x 96 cols): q|k|v head-slices
            {
                const int kl = tid >> 4;
                const int c  = (tid & 15) * 2;
                const size_t wrow = (size_t)(kk * 16 + kl) * NC + h * NDH + c;
                const float2 q2 = *(const float2*)&wq[wrow];
                const float2 k2 = *(const float2*)&wk[wrow];
                const float2 v2 = *(const float2*)&wv[wrow];
                wt[kl][c]      = q2.x; wt[kl][c + 1]      = q2.y;
                wt[kl][32 + c] = k2.x; wt[kl][32 + c + 1] = k2.y;
                wt[kl][64 + c] = v2.x; wt[kl][64 + c + 1] = v2.y;
            }
            __syncthreads();
            #pragma unroll
            for (int k = 0; k < 16; ++k) {
                float a[4];
                { const float4 t4 = *(const float4*)&xs[k][tr * 4];
                  a[0] = t4.x; a[1] = t4.y; a[2] = t4.z; a[3] = t4.w; }
                float bw[6];
                { const float2 b0 = *(const float2*)&wt[k][tc * 6];
                  const float2 b1_ = *(const float2*)&wt[k][tc * 6 + 2];
                  const float2 b2_ = *(const float2*)&wt[k][tc * 6 + 4];
                  bw[0] = b0.x; bw[1] = b0.y; bw[2] = b1_.x;
                  bw[3] = b1_.y; bw[4] = b2_.x; bw[5] = b2_.y; }
                #pragma unroll
                for (int i = 0; i < 4; ++i)
                    #pragma unroll
                    for (int j = 0; j < 6; ++j) acc[i][j] += a[i] * bw[j];
            }
            __syncthreads();
        }

        // scatter q/k/v to LDS (+ biases; k has no bias)
        #pragma unroll
        for (int i = 0; i < 4; ++i) {
            const int row = tr * 4 + i;
            #pragma unroll
            for (int j = 0; j < 6; ++j) {
                const int col = tc * 6 + j;
                float v = acc[i][j];
                if (col < 32)       qsT[col][row]      = v + bq[h * NDH + col];
                else if (col < 64)  ksT[col - 32][row] = v;
                else                vs[row][col - 64]  = v + bv[h * NDH + col - 64];
            }
        }
        __syncthreads();

        // norms
        if (tid < 64) {
            float s = 0.f;
            #pragma unroll
            for (int d = 0; d < 32; ++d) { float t = qsT[d][tid]; s += t * t; }
            qn[tid] = sqrtf(s);
        } else if (tid < 128) {
            const int c = tid - 64;
            float s = 0.f;
            #pragma unroll
            for (int d = 0; d < 32; ++d) { float t = ksT[d][c]; s += t * t; }
            kn[c] = sqrtf(s);
        }
        __syncthreads();

        // ---------------- S = q.kT (64x64, K=32), 4x4 micro-tile ----------------
        float sacc[4][4];
        #pragma unroll
        for (int i = 0; i < 4; ++i)
            #pragma unroll
            for (int j = 0; j < 4; ++j) sacc[i][j] = 0.0f;

        #pragma unroll
        for (int dd = 0; dd < 32; ++dd) {
            float qv[4], kv[4];
            { const float4 t4 = *(const float4*)&qsT[dd][tr * 4];
              qv[0] = t4.x; qv[1] = t4.y; qv[2] = t4.z; qv[3] = t4.w; }
            { const float4 t4 = *(const float4*)&ksT[dd][tc * 4];
              kv[0] = t4.x; kv[1] = t4.y; kv[2] = t4.z; kv[3] = t4.w; }
            #pragma unroll
            for (int i = 0; i < 4; ++i)
                #pragma unroll
                for (int j = 0; j < 4; ++j) sacc[i][j] += qv[i] * kv[j];
        }

        // scale by 1/denom*ls, add bias + mask
        float qn4[4], kn4[4];
        { const float4 t4 = *(const float4*)&qn[tr * 4];
          qn4[0] = t4.x; qn4[1] = t4.y; qn4[2] = t4.z; qn4[3] = t4.w; }
        { const float4 t4 = *(const float4*)&kn[tc * 4];
          kn4[0] = t4.x; kn4[1] = t4.y; kn4[2] = t4.z; kn4[3] = t4.w; }
        #pragma unroll
        for (int i = 0; i < 4; ++i) {
            const int row = tr * 4 + i;
            const float4 b4 = *(const float4*)&bias[(size_t)h * 4096 + row * 64 + tc * 4];
            const float4 m4 = *(const float4*)&mask[(size_t)b * 4096 + row * 64 + tc * 4];
            float bm[4] = {b4.x + m4.x, b4.y + m4.y, b4.z + m4.z, b4.w + m4.w};
            #pragma unroll
            for (int j = 0; j < 4; ++j) {
                const float denom = fmaxf(qn4[i] * kn4[j], 1e-6f);
                sacc[i][j] = sacc[i][j] / denom * ls + bm[j];
            }
        }

        // softmax over each row (16 lanes per row-group share the row)
        #pragma unroll
        for (int i = 0; i < 4; ++i) {
            float m = fmaxf(fmaxf(sacc[i][0], sacc[i][1]), fmaxf(sacc[i][2], sacc[i][3]));
            #pragma unroll
            for (int off = 1; off < 16; off <<= 1) m = fmaxf(m, __shfl_xor(m, off, 64));
            float e[4], s = 0.f;
            #pragma unroll
            for (int j = 0; j < 4; ++j) { e[j] = __expf(sacc[i][j] - m); s += e[j]; }
            #pragma unroll
            for (int off = 1; off < 16; off <<= 1) s += __shfl_xor(s, off, 64);
            const float inv = 1.0f / s;
            float4 p4;
            p4.x = e[0] * inv; p4.y = e[1] * inv; p4.z = e[2] * inv; p4.w = e[3] * inv;
            *(float4*)&Ss[tr * 4 + i][tc * 4] = p4;
        }
        __syncthreads();

        // ---------------- O = P @ v (64x32), 4x2 micro-tile ----------------
        float oacc[4][2];
        #pragma unroll
        for (int i = 0; i < 4; ++i) { oacc[i][0] = 0.f; oacc[i][1] = 0.f; }

        #pragma unroll
        for (int c4 = 0; c4 < 16; ++c4) {
            float p[4][4];
            #pragma unroll
            for (int i = 0; i < 4; ++i) {
                const float4 t4 = *(const float4*)&Ss[tr * 4 + i][c4 * 4];
                p[i][0] = t4.x; p[i][1] = t4.y; p[i][2] = t4.z; p[i][3] = t4.w;
            }
            #pragma unroll
            for (int cc = 0; cc < 4; ++cc) {
                const float2 v2 = *(const float2*)&vs[c4 * 4 + cc][tc * 2];
                #pragma unroll
                for (int i = 0; i < 4; ++i) {
                    oacc[i][0] += p[i][cc] * v2.x;
                    oacc[i][1] += p[i][cc] * v2.y;
                }
            }
        }
        #pragma unroll
        for (int i = 0; i < 4; ++i) {
            float2 o2; o2.x = oacc[i][0]; o2.y = oacc[i][1];
            *(float2*)&out[((size_t)b * NTOK + tr * 4 + i) * NC + h * NDH + tc * 2] = o2;
        }
        __syncthreads();   // protect LDS before next head restages
    }
}

// ---------------------------------------------------------------------------
// K3: output projection, IN-PLACE on d_out.
//   grid = 4608 blocks x 16 rows; rows staged to LDS before overwrite
//   (rows are block-private -> in-place safe).
// ---------------------------------------------------------------------------
__global__ __launch_bounds__(256) void proj_kernel(
    const float* __restrict__ wproj, const float* __restrict__ bproj,
    float* __restrict__ out)
{
    __shared__ float xsh[16][388];
    __shared__ float wsh[16][384];
    const int tid = threadIdx.x;
    const size_t r0 = (size_t)blockIdx.x * 16;

    // stage this block's 16 input rows
    {
        const int row = tid >> 4;
        const int cb  = (tid & 15) * 24;
        #pragma unroll
        for (int e = 0; e < 6; ++e) {
            const float4 v = *(const float4*)&out[(r0 + row) * NC + cb + e * 4];
            *(float4*)&xsh[row][cb + e * 4] = v;
        }
    }
    __syncthreads();

    const int rg = tid >> 6;   // 0..3  -> rows rg*4..rg*4+3
    const int cg = tid & 63;   // 0..63 -> cols cg + 64*j
    float acc[4][6];
    #pragma unroll
    for (int i = 0; i < 4; ++i)
        #pragma unroll
        for (int j = 0; j < 6; ++j) acc[i][j] = 0.0f;

    for (int kk = 0; kk < 24; ++kk) {
        {
            const int kl = tid >> 4;
            const int cb = (tid & 15) * 24;
            #pragma unroll
            for (int e = 0; e < 6; ++e) {
                const float4 v = *(const float4*)&wproj[(size_t)(kk * 16 + kl) * NC + cb + e * 4];
                *(float4*)&wsh[kl][cb + e * 4] = v;
            }
        }
        __syncthreads();
        #pragma unroll
        for (int k = 0; k < 16; ++k) {
            float a[4];
            #pragma unroll
            for (int i = 0; i < 4; ++i) a[i] = xsh[rg * 4 + i][kk * 16 + k];
            #pragma unroll
            for (int j = 0; j < 6; ++j) {
                const float bw = wsh[k][cg + 64 * j];
                #pragma unroll
                for (int i = 0; i < 4; ++i) acc[i][j] += a[i] * bw;
            }
        }
        __syncthreads();
    }

    #pragma unroll
    for (int i = 0; i < 4; ++i)
        #pragma unroll
        for (int j = 0; j < 6; ++j)
            out[(r0 + rg * 4 + i) * NC + cg + 64 * j] = acc[i][j] + bproj[cg + 64 * j];
}

// ---------------------------------------------------------------------------
extern "C" void kernel_launch(void* const* d_in, const int* in_sizes, int n_in,
                              void* d_out, int out_size, void* d_ws, size_t ws_size,
                              hipStream_t stream) {
    (void)in_sizes; (void)n_in; (void)out_size; (void)ws_size;
    const float* x     = (const float*)d_in[0];
    const float* mask  = (const float*)d_in[1];
    const float* wq    = (const float*)d_in[2];
    const float* bq    = (const float*)d_in[3];
    const float* wk    = (const float*)d_in[4];
    const float* wv    = (const float*)d_in[5];
    const float* bv    = (const float*)d_in[6];
    const float* w1    = (const float*)d_in[7];
    const float* b1    = (const float*)d_in[8];
    const float* w2    = (const float*)d_in[9];
    const float* b2    = (const float*)d_in[10];
    const float* tau   = (const float*)d_in[11];
    const float* wproj = (const float*)d_in[12];
    const float* bproj = (const float*)d_in[13];
    float* out  = (float*)d_out;
    float* bias = (float*)d_ws;   // 12*64*64 floats = 196,608 B

    cpb_kernel<<<1, 256, 0, stream>>>(w1, b1, w2, b2, bias);
    attn_kernel<<<NB, 256, 0, stream>>>(x, mask, wq, bq, wk, wv, bv, tau, bias, out);
    proj_kernel<<<NB * 4, 256, 0, stream>>>(wproj, bproj, out);
}

// Round 2
// 1295.218 us; speedup vs baseline: 2.3266x; 2.3266x over previous
//
#include <hip/hip_runtime.h>
#include <math.h>

#define NB   1152
#define NTOK 64
#define NC   384
#define NH   12
#define NDH  32

typedef short short8 __attribute__((ext_vector_type(8)));
typedef float f32x4  __attribute__((ext_vector_type(4)));

__device__ __forceinline__ unsigned short f2bf(float f) {
    unsigned int u = __builtin_bit_cast(unsigned int, f);
    unsigned int r = u + 0x7fffu + ((u >> 16) & 1u);   // RNE
    return (unsigned short)(r >> 16);
}
__device__ __forceinline__ unsigned int pack2(float lo, float hi) {
    return (unsigned int)f2bf(lo) | ((unsigned int)f2bf(hi) << 16);
}
__device__ __forceinline__ float bf2f(unsigned short h) {
    return __builtin_bit_cast(float, (unsigned int)h << 16);
}
__device__ __forceinline__ f32x4 mfma_bf16(short8 a, short8 b, f32x4 c) {
    return __builtin_amdgcn_mfma_f32_16x16x32_bf16(a, b, c, 0, 0, 0);
}

// ---------------------------------------------------------------------------
// prep: transpose+convert weights to bf16 col-major (B-operand layout).
//   wT[col 0..1151][k 0..383]  (cols: 0..383 wq, 384..767 wk, 768..1151 wv)
//   wprojT[col 0..383][k 0..383]
// 294912 uint writes total -> grid 1152 x 256.
// ---------------------------------------------------------------------------
__global__ __launch_bounds__(256) void prep_kernel(
    const float* __restrict__ wq, const float* __restrict__ wk,
    const float* __restrict__ wv, const float* __restrict__ wproj,
    unsigned int* __restrict__ wT, unsigned int* __restrict__ wprojT)
{
    const int o2 = blockIdx.x * 256 + threadIdx.x;
    if (o2 < 221184) {
        const int col = o2 / 192, k2 = o2 % 192, k = k2 * 2;
        const float* src = (col < 384) ? wq : ((col < 768) ? wk : wv);
        const int c = (col < 384) ? col : ((col < 768) ? col - 384 : col - 768);
        const float a = src[(size_t)k * NC + c];
        const float b = src[(size_t)(k + 1) * NC + c];
        wT[col * 192 + k2] = pack2(a, b);
    } else {
        const int o = o2 - 221184;
        const int col = o / 192, k2 = o % 192, k = k2 * 2;
        const float a = wproj[(size_t)k * NC + col];
        const float b = wproj[(size_t)(k + 1) * NC + col];
        wprojT[col * 192 + k2] = pack2(a, b);
    }
}

// ---------------------------------------------------------------------------
// cpb: position-bias MLP (225 x (2->512->12)) + gather + 16*sigmoid.
// 1 block x 1024 threads; hidden dim split 4-way per position.
// ---------------------------------------------------------------------------
__global__ __launch_bounds__(1024) void cpb_kernel(
    const float* __restrict__ w1, const float* __restrict__ b1,
    const float* __restrict__ w2, const float* __restrict__ b2,
    float* __restrict__ bias)
{
    __shared__ float part[225][48];
    __shared__ float tbs[225][12];
    const int t = threadIdx.x;

    if (t < 900) {
        const int p = t >> 2, pi = t & 3;
        const int ip = p / 15, jp = p % 15;
        float u0 = (float)(jp - 7) * (8.0f / 7.0f);
        float u1 = (float)(ip - 7) * (8.0f / 7.0f);
        float s0 = (u0 > 0.f) ? 1.f : ((u0 < 0.f) ? -1.f : 0.f);
        float s1 = (u1 > 0.f) ? 1.f : ((u1 < 0.f) ? -1.f : 0.f);
        float in0 = s0 * log2f(fabsf(u0) + 1.0f) * (1.0f / 3.0f);
        float in1 = s1 * log2f(fabsf(u1) + 1.0f) * (1.0f / 3.0f);
        float a[12];
        #pragma unroll
        for (int m = 0; m < 12; ++m) a[m] = 0.f;
        for (int j = pi * 128; j < pi * 128 + 128; ++j) {
            float hh = fmaxf(in0 * w1[j] + in1 * w1[512 + j] + b1[j], 0.0f);
            #pragma unroll
            for (int m = 0; m < 12; ++m) a[m] += hh * w2[j * 12 + m];
        }
        #pragma unroll
        for (int m = 0; m < 12; ++m) part[p][pi * 12 + m] = a[m];
    }
    __syncthreads();
    if (t < 225) {
        #pragma unroll
        for (int m = 0; m < 12; ++m)
            tbs[t][m] = b2[m] + part[t][m] + part[t][12 + m] + part[t][24 + m] + part[t][36 + m];
    }
    __syncthreads();
    for (int i = t; i < NH * NTOK * NTOK; i += 1024) {
        const int h = i >> 12, rem = i & 4095;
        const int ti = rem >> 6, tj = rem & 63;
        const int dr = (ti >> 3) - (tj >> 3);
        const int dc = (ti & 7) - (tj & 7);
        const int p = (dr + 7) * 15 + (dc + 7);
        bias[i] = 16.0f / (1.0f + __expf(-tbs[p][h]));
    }
}

// ---------------------------------------------------------------------------
// attn: fused per-window QKV (MFMA) + cosine attention (MFMA S & PV).
// 1152 blocks x 256 threads (4 waves; wave w owns token stripe w*16..w*16+15).
// ---------------------------------------------------------------------------
__global__ __launch_bounds__(256) void attn_kernel(
    const float* __restrict__ x,    const float* __restrict__ mask,
    const float* __restrict__ bq,   const float* __restrict__ bv,
    const float* __restrict__ tau,  const unsigned short* __restrict__ wT,
    const float* __restrict__ bias, float* __restrict__ out)
{
    __shared__ unsigned short xs[64 * 72];   // x K-chunk (64 tok x 64 k), stride 72
    __shared__ unsigned short qs[64 * 40];   // q token-major (32 d + pad)
    __shared__ unsigned short ks[64 * 40];   // k token-major
    __shared__ unsigned short vT[32 * 72];   // v transposed [d][token]
    __shared__ unsigned short Ps[64 * 72];   // probs (unnormalized) token-major
    __shared__ float qn[64], kn[64], rs[64];

    const int tid  = threadIdx.x;
    const int b    = blockIdx.x;
    const int w    = tid >> 6;
    const int lane = tid & 63;
    const int quad = lane >> 4;
    const int lq   = lane & 15;
    const int tok0 = w * 16 + quad * 4;

    unsigned int* xsu = (unsigned int*)xs;

    for (int h = 0; h < NH; ++h) {
        const float ls = fmaxf(tau[h] + 2.302585093f, 0.01f);

        // ---------------- QKV: C(64x96) = x(64x384) @ wT-slices ----------------
        f32x4 acc[6];
        #pragma unroll
        for (int n = 0; n < 6; ++n) acc[n] = (f32x4){0.f, 0.f, 0.f, 0.f};

        int colbase[6];
        #pragma unroll
        for (int n = 0; n < 6; ++n) {
            const int grp = n >> 1;                 // 0=q,1=k,2=v
            colbase[n] = grp * 384 + h * 32 + (n & 1) * 16;
        }

        for (int ch = 0; ch < 6; ++ch) {
            // stage x chunk (64 tok x 64 k) fp32 -> bf16
            {
                const int rowb = tid >> 5, cu = tid & 31;
                #pragma unroll
                for (int e = 0; e < 8; ++e) {
                    const int row = rowb + e * 8;
                    const float2 xv = *(const float2*)&x[((size_t)b * NTOK + row) * NC + ch * 64 + cu * 2];
                    xsu[row * 36 + cu] = pack2(xv.x, xv.y);
                }
            }
            __syncthreads();
            #pragma unroll
            for (int st = 0; st < 2; ++st) {
                const short8 a = *(const short8*)&xs[(w * 16 + lq) * 72 + st * 32 + quad * 8];
                #pragma unroll
                for (int n = 0; n < 6; ++n) {
                    const int col = colbase[n] + lq;
                    const short8 bb = *(const short8*)&wT[(size_t)col * NC + ch * 64 + st * 32 + quad * 8];
                    acc[n] = mfma_bf16(a, bb, acc[n]);
                }
            }
            __syncthreads();
        }

        // epilogue: scatter q,k (token-major bf16) and v (transposed)
        #pragma unroll
        for (int n = 0; n < 2; ++n) {
            const float bqv = bq[h * 32 + n * 16 + lq];
            #pragma unroll
            for (int r = 0; r < 4; ++r)
                qs[(tok0 + r) * 40 + n * 16 + lq] = f2bf(acc[n][r] + bqv);
        }
        #pragma unroll
        for (int n = 2; n < 4; ++n) {
            #pragma unroll
            for (int r = 0; r < 4; ++r)
                ks[(tok0 + r) * 40 + (n - 2) * 16 + lq] = f2bf(acc[n][r]);
        }
        #pragma unroll
        for (int n = 4; n < 6; ++n) {
            const int d = (n - 4) * 16 + lq;
            const float bvv = bv[h * 32 + d];
            uint2 wv2;
            wv2.x = pack2(acc[n][0] + bvv, acc[n][1] + bvv);
            wv2.y = pack2(acc[n][2] + bvv, acc[n][3] + bvv);
            *(uint2*)&vT[d * 72 + tok0] = wv2;
        }
        __syncthreads();

        // norms (fp32, from the same bf16 values the MFMAs consume)
        if (tid < 64) {
            const unsigned int* qu = (const unsigned int*)qs + tid * 20;
            float s = 0.f;
            #pragma unroll
            for (int j = 0; j < 16; ++j) {
                const unsigned int u = qu[j];
                const float a = bf2f((unsigned short)(u & 0xffff));
                const float c = bf2f((unsigned short)(u >> 16));
                s += a * a + c * c;
            }
            qn[tid] = sqrtf(s);
        } else if (tid < 128) {
            const int tt = tid - 64;
            const unsigned int* ku = (const unsigned int*)ks + tt * 20;
            float s = 0.f;
            #pragma unroll
            for (int j = 0; j < 16; ++j) {
                const unsigned int u = ku[j];
                const float a = bf2f((unsigned short)(u & 0xffff));
                const float c = bf2f((unsigned short)(u >> 16));
                s += a * a + c * c;
            }
            kn[tt] = sqrtf(s);
        }
        __syncthreads();

        // ---------------- S = q @ kT (64x64, K=32) ----------------
        const short8 aq = *(const short8*)&qs[(w * 16 + lq) * 40 + quad * 8];
        float svf[4][4];
        {
            f32x4 sv[4];
            #pragma unroll
            for (int n = 0; n < 4; ++n) {
                const short8 bk = *(const short8*)&ks[(n * 16 + lq) * 40 + quad * 8];
                sv[n] = mfma_bf16(aq, bk, (f32x4){0.f, 0.f, 0.f, 0.f});
            }
            float qnr[4];
            #pragma unroll
            for (int r = 0; r < 4; ++r) qnr[r] = qn[tok0 + r];
            #pragma unroll
            for (int n = 0; n < 4; ++n) {
                const int col = n * 16 + lq;
                const float knc = kn[col];
                #pragma unroll
                for (int r = 0; r < 4; ++r) {
                    const int row = tok0 + r;
                    const float den = fmaxf(qnr[r] * knc, 1e-6f);
                    svf[n][r] = sv[n][r] / den * ls
                              + bias[h * 4096 + row * 64 + col]
                              + mask[(size_t)b * 4096 + row * 64 + col];
                }
            }
        }

        // softmax (rows live across the 16-lane lq group)
        float mx[4], sm[4];
        #pragma unroll
        for (int r = 0; r < 4; ++r) {
            float m = fmaxf(fmaxf(svf[0][r], svf[1][r]), fmaxf(svf[2][r], svf[3][r]));
            #pragma unroll
            for (int off = 1; off < 16; off <<= 1) m = fmaxf(m, __shfl_xor(m, off, 64));
            mx[r] = m;
        }
        #pragma unroll
        for (int r = 0; r < 4; ++r) sm[r] = 0.f;
        #pragma unroll
        for (int n = 0; n < 4; ++n)
            #pragma unroll
            for (int r = 0; r < 4; ++r) {
                const float e = __expf(svf[n][r] - mx[r]);
                svf[n][r] = e;
                sm[r] += e;
            }
        #pragma unroll
        for (int r = 0; r < 4; ++r) {
            #pragma unroll
            for (int off = 1; off < 16; off <<= 1) sm[r] += __shfl_xor(sm[r], off, 64);
        }
        #pragma unroll
        for (int n = 0; n < 4; ++n)
            #pragma unroll
            for (int r = 0; r < 4; ++r)
                Ps[(tok0 + r) * 72 + n * 16 + lq] = f2bf(svf[n][r]);
        if (lq == 0) {
            #pragma unroll
            for (int r = 0; r < 4; ++r) rs[tok0 + r] = sm[r];
        }
        __syncthreads();

        // ---------------- O = P @ v (64x32, K=64) ----------------
        f32x4 oa[2];
        oa[0] = (f32x4){0.f, 0.f, 0.f, 0.f};
        oa[1] = (f32x4){0.f, 0.f, 0.f, 0.f};
        #pragma unroll
        for (int st = 0; st < 2; ++st) {
            const short8 ap = *(const short8*)&Ps[(w * 16 + lq) * 72 + st * 32 + quad * 8];
            #pragma unroll
            for (int n = 0; n < 2; ++n) {
                const short8 bv_ = *(const short8*)&vT[(n * 16 + lq) * 72 + st * 32 + quad * 8];
                oa[n] = mfma_bf16(ap, bv_, oa[n]);
            }
        }
        float rsi[4];
        #pragma unroll
        for (int r = 0; r < 4; ++r) rsi[r] = 1.0f / rs[tok0 + r];
        #pragma unroll
        for (int n = 0; n < 2; ++n)
            #pragma unroll
            for (int r = 0; r < 4; ++r)
                out[((size_t)b * NTOK + tok0 + r) * NC + h * 32 + n * 16 + lq] = oa[n][r] * rsi[r];
        // next head's first chunk barrier orders PV reads vs. LDS overwrite
    }
}

// ---------------------------------------------------------------------------
// proj: out = out @ wproj + bproj, in-place MFMA GEMM.
// 1152 blocks x 256 (64-row tile each; block reads only its own rows).
// Wave w owns columns w*96..w*96+95 across all 4 row-tiles.
// ---------------------------------------------------------------------------
__global__ __launch_bounds__(256) void proj_kernel(
    const unsigned short* __restrict__ wprojT, const float* __restrict__ bproj,
    float* __restrict__ out)
{
    __shared__ unsigned short as_[64 * 72];
    unsigned int* asu = (unsigned int*)as_;

    const int tid  = threadIdx.x;
    const size_t r0 = (size_t)blockIdx.x * 64;
    const int w    = tid >> 6;
    const int lane = tid & 63;
    const int quad = lane >> 4;
    const int lq   = lane & 15;

    f32x4 acc[4][6];
    #pragma unroll
    for (int mt = 0; mt < 4; ++mt)
        #pragma unroll
        for (int n = 0; n < 6; ++n) acc[mt][n] = (f32x4){0.f, 0.f, 0.f, 0.f};

    for (int ch = 0; ch < 6; ++ch) {
        {
            const int rowb = tid >> 5, cu = tid & 31;
            #pragma unroll
            for (int e = 0; e < 8; ++e) {
                const int row = rowb + e * 8;
                const float2 xv = *(const float2*)&out[(r0 + row) * NC + ch * 64 + cu * 2];
                asu[row * 36 + cu] = pack2(xv.x, xv.y);
            }
        }
        __syncthreads();
        #pragma unroll
        for (int st = 0; st < 2; ++st) {
            short8 am[4];
            #pragma unroll
            for (int mt = 0; mt < 4; ++mt)
                am[mt] = *(const short8*)&as_[(mt * 16 + lq) * 72 + st * 32 + quad * 8];
            #pragma unroll
            for (int n = 0; n < 6; ++n) {
                const int col = w * 96 + n * 16 + lq;
                const short8 bb = *(const short8*)&wprojT[(size_t)col * NC + ch * 64 + st * 32 + quad * 8];
                #pragma unroll
                for (int mt = 0; mt < 4; ++mt) acc[mt][n] = mfma_bf16(am[mt], bb, acc[mt][n]);
            }
        }
        __syncthreads();
    }

    float bp[6];
    #pragma unroll
    for (int n = 0; n < 6; ++n) bp[n] = bproj[w * 96 + n * 16 + lq];
    #pragma unroll
    for (int mt = 0; mt < 4; ++mt)
        #pragma unroll
        for (int n = 0; n < 6; ++n)
            #pragma unroll
            for (int r = 0; r < 4; ++r)
                out[(r0 + mt * 16 + quad * 4 + r) * NC + w * 96 + n * 16 + lq] = acc[mt][n][r] + bp[n];
}

// ---------------------------------------------------------------------------
extern "C" void kernel_launch(void* const* d_in, const int* in_sizes, int n_in,
                              void* d_out, int out_size, void* d_ws, size_t ws_size,
                              hipStream_t stream) {
    (void)in_sizes; (void)n_in; (void)out_size; (void)ws_size;
    const float* x     = (const float*)d_in[0];
    const float* mask  = (const float*)d_in[1];
    const float* wq    = (const float*)d_in[2];
    const float* bq    = (const float*)d_in[3];
    const float* wk    = (const float*)d_in[4];
    const float* wv    = (const float*)d_in[5];
    const float* bv    = (const float*)d_in[6];
    const float* w1    = (const float*)d_in[7];
    const float* b1    = (const float*)d_in[8];
    const float* w2    = (const float*)d_in[9];
    const float* b2    = (const float*)d_in[10];
    const float* tau   = (const float*)d_in[11];
    const float* wproj = (const float*)d_in[12];
    const float* bproj = (const float*)d_in[13];
    float* out = (float*)d_out;

    // ws layout: wT (884736 B) | wprojT (294912 B) | bias (196608 B)  ~1.38 MB
    unsigned short* wT     = (unsigned short*)d_ws;
    unsigned short* wprojT = (unsigned short*)((char*)d_ws + 884736);
    float*          bias   = (float*)((char*)d_ws + 884736 + 294912);

    prep_kernel<<<1152, 256, 0, stream>>>(wq, wk, wv, wproj,
                                          (unsigned int*)wT, (unsigned int*)wprojT);
    cpb_kernel<<<1, 1024, 0, stream>>>(w1, b1, w2, b2, bias);
    attn_kernel<<<NB, 256, 0, stream>>>(x, mask, bq, bv, tau, wT, bias, out);
    proj_kernel<<<NB, 256, 0, stream>>>(wprojT, bproj, out);
}

// Round 3
// 679.974 us; speedup vs baseline: 4.4316x; 1.9048x over previous
//
#include <hip/hip_runtime.h>
#include <math.h>

#define NB   1152
#define NTOK 64
#define NC   384
#define NH   12
#define NDH  32

typedef short short8 __attribute__((ext_vector_type(8)));
typedef float f32x4  __attribute__((ext_vector_type(4)));

__device__ __forceinline__ unsigned short f2bf(float f) {
    unsigned int u = __builtin_bit_cast(unsigned int, f);
    unsigned int r = u + 0x7fffu + ((u >> 16) & 1u);   // RNE
    return (unsigned short)(r >> 16);
}
__device__ __forceinline__ unsigned int pack2(float lo, float hi) {
    return (unsigned int)f2bf(lo) | ((unsigned int)f2bf(hi) << 16);
}
__device__ __forceinline__ float bf2f(unsigned short h) {
    return __builtin_bit_cast(float, (unsigned int)h << 16);
}
__device__ __forceinline__ f32x4 mfma_bf16(short8 a, short8 b, f32x4 c) {
    return __builtin_amdgcn_mfma_f32_16x16x32_bf16(a, b, c, 0, 0, 0);
}

// XOR-swizzled 64x384 bf16 tile (no padding, 2-way-free bank pattern).
// Element (row, k): group g = k/8 is XORed with (row&7) at 16B granularity.
__device__ __forceinline__ short8 tile_afrag(const unsigned short* t, int row, int kq) {
    return *(const short8*)((const char*)t + row * 768 + ((kq ^ (row & 7)) << 4));
}

// ---------------------------------------------------------------------------
// prep: transpose+convert weights to bf16 col-major (B-operand layout).
//   wT[col 0..1151][k 0..383]  (cols: 0..383 wq, 384..767 wk, 768..1151 wv)
//   wprojT[col 0..383][k 0..383]
// ---------------------------------------------------------------------------
__global__ __launch_bounds__(256) void prep_kernel(
    const float* __restrict__ wq, const float* __restrict__ wk,
    const float* __restrict__ wv, const float* __restrict__ wproj,
    unsigned int* __restrict__ wT, unsigned int* __restrict__ wprojT)
{
    const int o2 = blockIdx.x * 256 + threadIdx.x;
    if (o2 < 221184) {
        const int col = o2 / 192, k2 = o2 % 192, k = k2 * 2;
        const float* src = (col < 384) ? wq : ((col < 768) ? wk : wv);
        const int c = (col < 384) ? col : ((col < 768) ? col - 384 : col - 768);
        const float a = src[(size_t)k * NC + c];
        const float b = src[(size_t)(k + 1) * NC + c];
        wT[col * 192 + k2] = pack2(a, b);
    } else {
        const int o = o2 - 221184;
        const int col = o / 192, k2 = o % 192, k = k2 * 2;
        const float a = wproj[(size_t)k * NC + col];
        const float b = wproj[(size_t)(k + 1) * NC + col];
        wprojT[col * 192 + k2] = pack2(a, b);
    }
}

// ---------------------------------------------------------------------------
// cpb MLP: 225 blocks x 1 wave; lane handles 8 hidden units, shfl-reduce.
// Writes tbs[225][12] (fp32) to workspace.
// ---------------------------------------------------------------------------
__global__ __launch_bounds__(64) void cpb_mlp_kernel(
    const float* __restrict__ w1, const float* __restrict__ b1,
    const float* __restrict__ w2, const float* __restrict__ b2,
    float* __restrict__ tbs)
{
    const int p = blockIdx.x;           // 0..224
    const int lane = threadIdx.x;       // 0..63
    const int ip = p / 15, jp = p % 15;
    float u0 = (float)(jp - 7) * (8.0f / 7.0f);
    float u1 = (float)(ip - 7) * (8.0f / 7.0f);
    float s0 = (u0 > 0.f) ? 1.f : ((u0 < 0.f) ? -1.f : 0.f);
    float s1 = (u1 > 0.f) ? 1.f : ((u1 < 0.f) ? -1.f : 0.f);
    float in0 = s0 * log2f(fabsf(u0) + 1.0f) * (1.0f / 3.0f);
    float in1 = s1 * log2f(fabsf(u1) + 1.0f) * (1.0f / 3.0f);

    float a[12];
    #pragma unroll
    for (int m = 0; m < 12; ++m) a[m] = 0.f;
    #pragma unroll
    for (int e = 0; e < 8; ++e) {
        const int j = lane * 8 + e;
        float hh = fmaxf(in0 * w1[j] + in1 * w1[512 + j] + b1[j], 0.0f);
        #pragma unroll
        for (int m = 0; m < 12; ++m) a[m] += hh * w2[j * 12 + m];
    }
    #pragma unroll
    for (int m = 0; m < 12; ++m) {
        #pragma unroll
        for (int off = 1; off < 64; off <<= 1) a[m] += __shfl_xor(a[m], off, 64);
    }
    if (lane < 12) tbs[p * 12 + lane] = a[lane] + b2[lane];
}

// bias gather: bias[h][ti][tj] = 16*sigmoid(tbs[relidx(ti,tj)][h])
__global__ __launch_bounds__(1024) void bias_gather_kernel(
    const float* __restrict__ tbs, float* __restrict__ bias)
{
    const int i = blockIdx.x * 1024 + threadIdx.x;
    if (i >= NH * NTOK * NTOK) return;
    const int h = i >> 12, rem = i & 4095;
    const int ti = rem >> 6, tj = rem & 63;
    const int dr = (ti >> 3) - (tj >> 3);
    const int dc = (ti & 7) - (tj & 7);
    const int p = (dr + 7) * 15 + (dc + 7);
    bias[i] = 16.0f / (1.0f + __expf(-tbs[p * 12 + h]));
}

// ---------------------------------------------------------------------------
// attn: fused per-window QKV (MFMA) + cosine attention (MFMA S & PV).
// 1152 blocks x 256 threads. x staged ONCE (swizzled bf16); K-loops
// barrier-free; 5 barriers/head around scatter/norms/softmax.
// ---------------------------------------------------------------------------
__global__ __launch_bounds__(256) void attn_kernel(
    const float* __restrict__ x,    const float* __restrict__ mask,
    const float* __restrict__ bq,   const float* __restrict__ bv,
    const float* __restrict__ tau,  const unsigned short* __restrict__ wT,
    const float* __restrict__ bias, float* __restrict__ out)
{
    __shared__ unsigned short xs[64 * 384];   // 49152 B, swizzled
    __shared__ unsigned short qk[5120];       // qs[64*40] | ks[64*40]; Ps aliases
    __shared__ unsigned short vT[32 * 72];    // v transposed [d][token]
    __shared__ float qn[64], kn[64], rs[64];

    unsigned short* qs = qk;
    unsigned short* ks = qk + 2560;
    unsigned short* Ps = qk;                  // alias (qs/ks dead when P written)

    const int tid  = threadIdx.x;
    const int b    = blockIdx.x;
    const int w    = tid >> 6;
    const int lane = tid & 63;
    const int quad = lane >> 4;
    const int lq   = lane & 15;
    const int tok0 = w * 16 + quad * 4;       // S/PV phase rows
    const int m0   = (w & 1) * 2;             // QKV: tile base (2 tiles)
    const int n0   = (w >> 1) * 3;            // QKV: col-frag base (3 frags)

    unsigned int* xsu = (unsigned int*)xs;

    // ---- stage x once: 64 tok x 384 k, fp32 -> bf16, swizzled ----
    {
        const int row = tid >> 2;             // 0..63
        const int q4  = tid & 3;              // 0..3 (96-k quarter)
        const float* xr = &x[((size_t)b * NTOK + row) * NC + q4 * 96];
        #pragma unroll
        for (int e = 0; e < 24; ++e) {
            const float4 xv = *(const float4*)&xr[e * 4];
            const int p = q4 * 48 + e * 2;    // uint index within row (unswizzled)
            const int g = p >> 2;
            const int u = row * 192 + (((g ^ (row & 7)) << 2) | (p & 3));
            uint2 w2;
            w2.x = pack2(xv.x, xv.y);
            w2.y = pack2(xv.z, xv.w);
            *(uint2*)&xsu[u] = w2;
        }
    }
    __syncthreads();

    for (int h = 0; h < NH; ++h) {
        const float ls = fmaxf(tau[h] + 2.302585093f, 0.01f);

        // ---------- QKV: C(64x96) = x @ wT-slices, barrier-free ----------
        f32x4 acc[2][3];
        #pragma unroll
        for (int mi = 0; mi < 2; ++mi)
            #pragma unroll
            for (int ni = 0; ni < 3; ++ni) acc[mi][ni] = (f32x4){0.f, 0.f, 0.f, 0.f};

        const unsigned short* bp[3];
        #pragma unroll
        for (int ni = 0; ni < 3; ++ni) {
            const int nf = n0 + ni;
            const int col = (nf >> 1) * 384 + h * 32 + (nf & 1) * 16 + lq;
            bp[ni] = wT + (size_t)col * NC + quad * 8;
        }

        for (int ksI = 0; ksI < 12; ++ksI) {
            short8 a0 = tile_afrag(xs, m0 * 16 + lq,       ksI * 4 + quad);
            short8 a1 = tile_afrag(xs, (m0 + 1) * 16 + lq, ksI * 4 + quad);
            #pragma unroll
            for (int ni = 0; ni < 3; ++ni) {
                const short8 bb = *(const short8*)&bp[ni][ksI * 32];
                acc[0][ni] = mfma_bf16(a0, bb, acc[0][ni]);
                acc[1][ni] = mfma_bf16(a1, bb, acc[1][ni]);
            }
        }

        __syncthreads();   // WAR: prior head's PV reads of Ps/vT complete

        // ---------- scatter q/k/v (+biases) ----------
        #pragma unroll
        for (int mi = 0; mi < 2; ++mi) {
            const int t0 = (m0 + mi) * 16 + quad * 4;
            #pragma unroll
            for (int ni = 0; ni < 3; ++ni) {
                const int nf = n0 + ni;
                const int d  = (nf & 1) * 16 + lq;
                if (nf < 2) {
                    const float bb = bq[h * 32 + d];
                    #pragma unroll
                    for (int r = 0; r < 4; ++r)
                        qs[(t0 + r) * 40 + d] = f2bf(acc[mi][ni][r] + bb);
                } else if (nf < 4) {
                    #pragma unroll
                    for (int r = 0; r < 4; ++r)
                        ks[(t0 + r) * 40 + d] = f2bf(acc[mi][ni][r]);
                } else {
                    const float bb = bv[h * 32 + d];
                    uint2 u2;
                    u2.x = pack2(acc[mi][ni][0] + bb, acc[mi][ni][1] + bb);
                    u2.y = pack2(acc[mi][ni][2] + bb, acc[mi][ni][3] + bb);
                    *(uint2*)&vT[d * 72 + t0] = u2;
                }
            }
        }
        __syncthreads();

        // ---------- norms ----------
        if (tid < 64) {
            const unsigned int* qu = (const unsigned int*)qs + tid * 20;
            float s = 0.f;
            #pragma unroll
            for (int j = 0; j < 16; ++j) {
                const unsigned int u = qu[j];
                const float a = bf2f((unsigned short)(u & 0xffff));
                const float c = bf2f((unsigned short)(u >> 16));
                s += a * a + c * c;
            }
            qn[tid] = sqrtf(s);
        } else if (tid < 128) {
            const int tt = tid - 64;
            const unsigned int* ku = (const unsigned int*)ks + tt * 20;
            float s = 0.f;
            #pragma unroll
            for (int j = 0; j < 16; ++j) {
                const unsigned int u = ku[j];
                const float a = bf2f((unsigned short)(u & 0xffff));
                const float c = bf2f((unsigned short)(u >> 16));
                s += a * a + c * c;
            }
            kn[tt] = sqrtf(s);
        }
        __syncthreads();

        // ---------- S = q @ kT (wave w owns m-tile w) ----------
        const short8 aq = *(const short8*)&qs[(w * 16 + lq) * 40 + quad * 8];
        float svf[4][4];
        {
            float qnr[4];
            #pragma unroll
            for (int r = 0; r < 4; ++r) qnr[r] = qn[tok0 + r];
            #pragma unroll
            for (int n = 0; n < 4; ++n) {
                const short8 bk = *(const short8*)&ks[(n * 16 + lq) * 40 + quad * 8];
                const f32x4 sv = mfma_bf16(aq, bk, (f32x4){0.f, 0.f, 0.f, 0.f});
                const int col = n * 16 + lq;
                const float knc = kn[col];
                #pragma unroll
                for (int r = 0; r < 4; ++r) {
                    const int row = tok0 + r;
                    const float den = fmaxf(qnr[r] * knc, 1e-6f);
                    svf[n][r] = sv[r] / den * ls
                              + bias[h * 4096 + row * 64 + col]
                              + mask[(size_t)b * 4096 + row * 64 + col];
                }
            }
        }

        // softmax across the 16-lane lq group
        float mx[4], sm[4];
        #pragma unroll
        for (int r = 0; r < 4; ++r) {
            float m = fmaxf(fmaxf(svf[0][r], svf[1][r]), fmaxf(svf[2][r], svf[3][r]));
            #pragma unroll
            for (int off = 1; off < 16; off <<= 1) m = fmaxf(m, __shfl_xor(m, off, 64));
            mx[r] = m; sm[r] = 0.f;
        }
        #pragma unroll
        for (int n = 0; n < 4; ++n)
            #pragma unroll
            for (int r = 0; r < 4; ++r) {
                const float e = __expf(svf[n][r] - mx[r]);
                svf[n][r] = e; sm[r] += e;
            }
        #pragma unroll
        for (int r = 0; r < 4; ++r) {
            #pragma unroll
            for (int off = 1; off < 16; off <<= 1) sm[r] += __shfl_xor(sm[r], off, 64);
        }

        __syncthreads();   // all S reads of qs/ks done before Ps overwrite

        #pragma unroll
        for (int n = 0; n < 4; ++n)
            #pragma unroll
            for (int r = 0; r < 4; ++r)
                Ps[(tok0 + r) * 72 + n * 16 + lq] = f2bf(svf[n][r]);
        if (lq == 0) {
            #pragma unroll
            for (int r = 0; r < 4; ++r) rs[tok0 + r] = sm[r];
        }
        __syncthreads();

        // ---------- O = P @ v ----------
        f32x4 oa[2];
        oa[0] = (f32x4){0.f, 0.f, 0.f, 0.f};
        oa[1] = (f32x4){0.f, 0.f, 0.f, 0.f};
        #pragma unroll
        for (int st = 0; st < 2; ++st) {
            const short8 ap = *(const short8*)&Ps[(w * 16 + lq) * 72 + st * 32 + quad * 8];
            #pragma unroll
            for (int n = 0; n < 2; ++n) {
                const short8 bv_ = *(const short8*)&vT[(n * 16 + lq) * 72 + st * 32 + quad * 8];
                oa[n] = mfma_bf16(ap, bv_, oa[n]);
            }
        }
        float rsi[4];
        #pragma unroll
        for (int r = 0; r < 4; ++r) rsi[r] = 1.0f / rs[tok0 + r];
        #pragma unroll
        for (int n = 0; n < 2; ++n)
            #pragma unroll
            for (int r = 0; r < 4; ++r)
                out[((size_t)b * NTOK + tok0 + r) * NC + h * 32 + n * 16 + lq] = oa[n][r] * rsi[r];
    }
}

// ---------------------------------------------------------------------------
// proj: out = out @ wproj + bproj, in-place. 1152 blocks x 256.
// Stage 64x384 tile once (swizzled bf16), then 288 MFMAs/wave barrier-free.
// ---------------------------------------------------------------------------
__global__ __launch_bounds__(256) void proj_kernel(
    const unsigned short* __restrict__ wprojT, const float* __restrict__ bproj,
    float* __restrict__ out)
{
    __shared__ unsigned short as_[64 * 384];  // 49152 B, swizzled
    unsigned int* asu = (unsigned int*)as_;

    const int tid  = threadIdx.x;
    const size_t r0 = (size_t)blockIdx.x * 64;
    const int w    = tid >> 6;
    const int lane = tid & 63;
    const int quad = lane >> 4;
    const int lq   = lane & 15;

    {
        const int row = tid >> 2;
        const int q4  = tid & 3;
        const float* xr = &out[(r0 + row) * NC + q4 * 96];
        #pragma unroll
        for (int e = 0; e < 24; ++e) {
            const float4 xv = *(const float4*)&xr[e * 4];
            const int p = q4 * 48 + e * 2;
            const int g = p >> 2;
            const int u = row * 192 + (((g ^ (row & 7)) << 2) | (p & 3));
            uint2 w2;
            w2.x = pack2(xv.x, xv.y);
            w2.y = pack2(xv.z, xv.w);
            *(uint2*)&asu[u] = w2;
        }
    }
    __syncthreads();

    f32x4 acc[4][6];
    #pragma unroll
    for (int mt = 0; mt < 4; ++mt)
        #pragma unroll
        for (int n = 0; n < 6; ++n) acc[mt][n] = (f32x4){0.f, 0.f, 0.f, 0.f};

    const unsigned short* bp[6];
    #pragma unroll
    for (int n = 0; n < 6; ++n)
        bp[n] = wprojT + (size_t)(w * 96 + n * 16 + lq) * NC + quad * 8;

    for (int ksI = 0; ksI < 12; ++ksI) {
        short8 am[4];
        #pragma unroll
        for (int mt = 0; mt < 4; ++mt)
            am[mt] = tile_afrag(as_, mt * 16 + lq, ksI * 4 + quad);
        #pragma unroll
        for (int n = 0; n < 6; ++n) {
            const short8 bb = *(const short8*)&bp[n][ksI * 32];
            #pragma unroll
            for (int mt = 0; mt < 4; ++mt) acc[mt][n] = mfma_bf16(am[mt], bb, acc[mt][n]);
        }
    }

    float bpv[6];
    #pragma unroll
    for (int n = 0; n < 6; ++n) bpv[n] = bproj[w * 96 + n * 16 + lq];
    #pragma unroll
    for (int mt = 0; mt < 4; ++mt)
        #pragma unroll
        for (int n = 0; n < 6; ++n)
            #pragma unroll
            for (int r = 0; r < 4; ++r)
                out[(r0 + mt * 16 + quad * 4 + r) * NC + w * 96 + n * 16 + lq]
                    = acc[mt][n][r] + bpv[n];
}

// ---------------------------------------------------------------------------
extern "C" void kernel_launch(void* const* d_in, const int* in_sizes, int n_in,
                              void* d_out, int out_size, void* d_ws, size_t ws_size,
                              hipStream_t stream) {
    (void)in_sizes; (void)n_in; (void)out_size; (void)ws_size;
    const float* x     = (const float*)d_in[0];
    const float* mask  = (const float*)d_in[1];
    const float* wq    = (const float*)d_in[2];
    const float* bq    = (const float*)d_in[3];
    const float* wk    = (const float*)d_in[4];
    const float* wv    = (const float*)d_in[5];
    const float* bv    = (const float*)d_in[6];
    const float* w1    = (const float*)d_in[7];
    const float* b1    = (const float*)d_in[8];
    const float* w2    = (const float*)d_in[9];
    const float* b2    = (const float*)d_in[10];
    const float* tau   = (const float*)d_in[11];
    const float* wproj = (const float*)d_in[12];
    const float* bproj = (const float*)d_in[13];
    float* out = (float*)d_out;

    // ws: wT 884736 | wprojT 294912 | bias 196608 | tbs 10800  (~1.39 MB)
    unsigned short* wT     = (unsigned short*)d_ws;
    unsigned short* wprojT = (unsigned short*)((char*)d_ws + 884736);
    float*          bias   = (float*)((char*)d_ws + 884736 + 294912);
    float*          tbs    = (float*)((char*)d_ws + 884736 + 294912 + 196608);

    prep_kernel<<<1152, 256, 0, stream>>>(wq, wk, wv, wproj,
                                          (unsigned int*)wT, (unsigned int*)wprojT);
    cpb_mlp_kernel<<<225, 64, 0, stream>>>(w1, b1, w2, b2, tbs);
    bias_gather_kernel<<<48, 1024, 0, stream>>>(tbs, bias);
    attn_kernel<<<NB, 256, 0, stream>>>(x, mask, bq, bv, tau, wT, bias, out);
    proj_kernel<<<NB, 256, 0, stream>>>(wprojT, bproj, out);
}